// Round 2
// baseline (634.193 us; speedup 1.0000x reference)
//
#include <hip/hip_runtime.h>
#include <stdint.h>

#define KTAPS 8
#define C 32
#define RPB 128            // out-rows per bucket: 400000 = 3125 * 128 exactly
#define NB 3125            // buckets
#define NL (NB * KTAPS)    // 25000 (bucket,k) lists
#define SEGCAP 128         // capacity per (bucket,k) list; Poisson(64), P(>128) ~ 1e-13
#define LDSS 33            // LDS tile row stride: bank = (row+ch)%32 -> spread
#define OMAX 8192

// ---------------------------------------------------------------------------
// init: zero the 25000 list counters + ocount (+pad).
// ---------------------------------------------------------------------------
__global__ __launch_bounds__(256) void init_kernel(
    unsigned int* __restrict__ cnt, int n4) {
  int i = blockIdx.x * 256 + threadIdx.x;
  if (i < n4) ((uint4*)cnt)[i] = make_uint4(0u, 0u, 0u, 0u);
}

// ---------------------------------------------------------------------------
// phase A: bin rules by (ro>>7, k). Entry packs (ro&127)<<21 | ri  (28 bits).
// k = blockIdx.y (block-uniform). Scattered 4B stores land on the 25K hot
// tail lines (3.2 MB/XCD) -> coalesce in L2, no bidx-style write-amp.
// Counter atomics: 1.6M dwords (~6us at measured fabric atomic rate).
// ---------------------------------------------------------------------------
__global__ __launch_bounds__(256) void bin_kernel(
    const int* __restrict__ rules_in, const int* __restrict__ rules_out,
    unsigned int* __restrict__ cnt, unsigned int* __restrict__ bins,
    uint4* __restrict__ oflow, unsigned int* __restrict__ ocount, int R) {
  const int k = blockIdx.y;
  const int r = blockIdx.x * 256 + threadIdx.x;
  if (r >= R) return;
  const unsigned int ri = (unsigned int)rules_in[(size_t)k * R + r];
  const unsigned int ro = (unsigned int)rules_out[(size_t)k * R + r];
  const unsigned int list = (ro >> 7) * (unsigned)KTAPS + (unsigned)k;
  const unsigned int idx = atomicAdd(cnt + list, 1u);
  if (idx < (unsigned)SEGCAP) {
    bins[(size_t)list * SEGCAP + idx] = ((ro & 127u) << 21) | ri;
  } else {
    unsigned int j = atomicAdd(ocount, 1u);
    if (j < (unsigned)OMAX) oflow[j] = make_uint4(ro, ri, (unsigned)k, 0u);
  }
}

// ---------------------------------------------------------------------------
// phase B: one block per bucket OWNS 128 out rows -> no global atomics.
// Flat entry index f walks the 8 k-segments, each padded to a multiple of 64
// so k is wave-uniform (scalar-pipe W, as in the proven GEMM shape).
// Accumulate into LDS tile via ds_add_f32 (step j: bank=(rl+j)%32, ~2-way).
// Epilogue streams tile+bias -> out exactly once (no bias_init kernel).
// ---------------------------------------------------------------------------
__global__ __launch_bounds__(256) void gemm_bucket_kernel(
    const float* __restrict__ in, const float* __restrict__ w,
    const unsigned int* __restrict__ cnt, const unsigned int* __restrict__ bins,
    const float* __restrict__ bias, float* __restrict__ out) {
  __shared__ float tile[RPB * LDSS];   // 16.9 KB -> LDS allows 8 blocks/CU
  const int b   = blockIdx.x;
  const int tid = threadIdx.x;

  // zero the tile
  for (int i = tid; i < RPB * LDSS; i += 256) tile[i] = 0.f;

  // segment counts + padded prefix (uniform; compile-time-indexed arrays only)
  unsigned int cn[KTAPS], ps[KTAPS], T = 0;
#pragma unroll
  for (int kk = 0; kk < KTAPS; ++kk) {
    unsigned int c = cnt[b * KTAPS + kk];
    if (c > (unsigned)SEGCAP) c = SEGCAP;
    cn[kk] = c; ps[kk] = T; T += (c + 63u) & ~63u;
  }
  __syncthreads();   // tile zeroed before any ds_add

  for (unsigned int f = tid; f < T; f += 256) {
    // segment search: k = max{kk : ps[kk] <= f}; padding => wave-uniform
    int k = 0;
#pragma unroll
    for (int kk = 1; kk < KTAPS; ++kk) if (f >= ps[kk]) k = kk;
    k = __builtin_amdgcn_readfirstlane(k);
    unsigned int psk = ps[0], cnk = cn[0];
#pragma unroll
    for (int kk = 1; kk < KTAPS; ++kk)
      if (k == kk) { psk = ps[kk]; cnk = cn[kk]; }

    const unsigned int i = f - psk;
    if (i < cnk) {
      const unsigned int e  = bins[((size_t)b * KTAPS + k) * SEGCAP + i];
      const unsigned int ri = e & 0x1FFFFFu;
      const unsigned int rl = (e >> 21) & 127u;

      // 8 independent 16B gathers -- all in flight together
      const float4* rowp = (const float4*)(in + (size_t)ri * C);
      float4 av[8];
#pragma unroll
      for (int j = 0; j < 8; ++j) av[j] = rowp[j];

      float a[C];
#pragma unroll
      for (int j = 0; j < 8; ++j) {
        a[4 * j + 0] = av[j].x; a[4 * j + 1] = av[j].y;
        a[4 * j + 2] = av[j].z; a[4 * j + 3] = av[j].w;
      }

      const float* wk = w + k * (C * C);   // wave-uniform -> scalar pipe
      float acc[C];
#pragma unroll
      for (int co = 0; co < C; ++co) acc[co] = a[0] * wk[co];
#pragma unroll
      for (int ci = 1; ci < C; ++ci)
#pragma unroll
        for (int co = 0; co < C; ++co)
          acc[co] = fmaf(a[ci], wk[ci * C + co], acc[co]);

      float* trow = tile + rl * LDSS;
#pragma unroll
      for (int j = 0; j < C; ++j) atomicAdd(trow + j, acc[j]);  // ds_add_f32
    }
  }

  __syncthreads();

  // epilogue: 256 threads = 128 rows x 2 halves; bias in-register; pure store
  const int row = tid >> 1, half = tid & 1;
  const float4* bp = (const float4*)bias;
  float4 bv[4];
#pragma unroll
  for (int jj = 0; jj < 4; ++jj) bv[jj] = bp[half * 4 + jj];
  float* op = out + ((size_t)b * RPB + row) * C + half * 16;
  const float* trow = tile + row * LDSS + half * 16;
#pragma unroll
  for (int jj = 0; jj < 4; ++jj) {
    float4 v;
    v.x = trow[jj * 4 + 0] + bv[jj].x;
    v.y = trow[jj * 4 + 1] + bv[jj].y;
    v.z = trow[jj * 4 + 2] + bv[jj].z;
    v.w = trow[jj * 4 + 3] + bv[jj].w;
    ((float4*)op)[jj] = v;
  }
}

// ---------------------------------------------------------------------------
// overflow fixup (expected 0 entries): lane=co, broadcast a-row loads.
// ---------------------------------------------------------------------------
__global__ __launch_bounds__(256) void oflow_kernel(
    const uint4* __restrict__ oflow, const unsigned int* __restrict__ ocount,
    const float* __restrict__ in, const float* __restrict__ w,
    float* __restrict__ out) {
  const int g  = threadIdx.x >> 5;
  const int co = threadIdx.x & 31;
  unsigned int n = *ocount;
  if (n > (unsigned)OMAX) n = (unsigned)OMAX;
  for (unsigned int e = g; e < n; e += 8) {
    const uint4 ent = oflow[e];      // (ro, ri, k)
    const float* ap = in + (size_t)ent.y * C;
    const float* wk = w + ent.z * (C * C);
    float acc = 0.f;
#pragma unroll
    for (int ci = 0; ci < C; ++ci) acc = fmaf(ap[ci], wk[ci * C + co], acc);
    unsafeAtomicAdd(out + (size_t)ent.x * C + co, acc);
  }
}

// ---------------------------------------------------------------------------
// fallback (workspace too small): round-1 fused atomic path.
// ---------------------------------------------------------------------------
__global__ __launch_bounds__(256) void bias_init_kernel(
    float* __restrict__ out, const float* __restrict__ bias, int n4) {
  int idx = blockIdx.x * 256 + threadIdx.x;
  if (idx >= n4) return;
  ((float4*)out)[idx] = ((const float4*)bias)[idx & 7];
}

__global__ __launch_bounds__(256) void fused_scatter_kernel(
    const float* __restrict__ in, const float* __restrict__ w,
    const int* __restrict__ rules_in, const int* __restrict__ rules_out,
    float* __restrict__ out, int R) {
  __shared__ float cbuf[256 * LDSS];
  __shared__ int   robuf[256];
  const int k = blockIdx.y, tid = threadIdx.x;
  const int r = blockIdx.x * 256 + tid;
  const int lane = tid & 63, wbase = tid & ~63;
  if (blockIdx.x * 256 + wbase >= R) return;
  const bool valid = (r < R);
  const int rc = valid ? r : (R - 1);
  const int ri = rules_in[(size_t)k * R + rc];
  const int ro = valid ? rules_out[(size_t)k * R + rc] : -1;
  robuf[tid] = ro;
  const float4* rowp = (const float4*)(in + (size_t)ri * C);
  float4 av[8];
#pragma unroll
  for (int j = 0; j < 8; ++j) av[j] = rowp[j];
  float a[C];
#pragma unroll
  for (int j = 0; j < 8; ++j) {
    a[4 * j + 0] = av[j].x; a[4 * j + 1] = av[j].y;
    a[4 * j + 2] = av[j].z; a[4 * j + 3] = av[j].w;
  }
  const float* wk = w + k * (C * C);
  float acc[C];
#pragma unroll
  for (int co = 0; co < C; ++co) acc[co] = a[0] * wk[co];
#pragma unroll
  for (int ci = 1; ci < C; ++ci)
#pragma unroll
    for (int co = 0; co < C; ++co)
      acc[co] = fmaf(a[ci], wk[ci * C + co], acc[co]);
  float* myrow = cbuf + tid * LDSS;
#pragma unroll
  for (int co = 0; co < C; ++co) myrow[co] = acc[co];
  const int co = lane & 31, half = lane >> 5;
#pragma unroll
  for (int j = 0; j < 32; ++j) {
    const int rl  = wbase + 2 * j + half;
    const int rol = robuf[rl];
    const float v = cbuf[rl * LDSS + co];
    if (rol >= 0) unsafeAtomicAdd(out + (size_t)rol * C + co, v);
  }
}

extern "C" void kernel_launch(void* const* d_in, const int* in_sizes, int n_in,
                              void* d_out, int out_size, void* d_ws, size_t ws_size,
                              hipStream_t stream) {
  const float* in_features = (const float*)d_in[0];
  const float* weight      = (const float*)d_in[1];
  const float* bias        = (const float*)d_in[2];
  const int*   rules_in    = (const int*)d_in[3];
  const int*   rules_out   = (const int*)d_in[4];

  const int R = in_sizes[3] / KTAPS;   // 200000
  float* out = (float*)d_out;

  // workspace layout
  const size_t n_cnt    = ((size_t)NL + 4 + 3) & ~(size_t)3;        // counters + ocount, uint4-padded
  const size_t cnt_b    = n_cnt * sizeof(unsigned int);             // ~100 KB
  const size_t bins_b   = (size_t)NL * SEGCAP * sizeof(unsigned int); // 12.8 MB
  const size_t oflow_b  = (size_t)OMAX * sizeof(uint4);             // 128 KB

  if (ws_size >= cnt_b + bins_b + oflow_b) {
    unsigned int* cnt    = (unsigned int*)d_ws;
    unsigned int* ocount = cnt + NL;
    unsigned int* bins   = (unsigned int*)((char*)d_ws + cnt_b);
    uint4*        oflow  = (uint4*)((char*)d_ws + cnt_b + bins_b);

    const int n4 = (int)(n_cnt / 4);
    init_kernel<<<(n4 + 255) / 256, 256, 0, stream>>>(cnt, n4);

    dim3 gridA((R + 255) / 256, KTAPS);
    bin_kernel<<<gridA, 256, 0, stream>>>(rules_in, rules_out, cnt, bins,
                                          oflow, ocount, R);

    gemm_bucket_kernel<<<NB, 256, 0, stream>>>(in_features, weight, cnt, bins,
                                               bias, out);

    oflow_kernel<<<1, 256, 0, stream>>>(oflow, ocount, in_features, weight, out);
  } else {
    const int n_out4 = out_size / 4;
    bias_init_kernel<<<(n_out4 + 255) / 256, 256, 0, stream>>>(out, bias, n_out4);
    dim3 grid((R + 255) / 256, KTAPS);
    fused_scatter_kernel<<<grid, 256, 0, stream>>>(in_features, weight, rules_in,
                                                   rules_out, out, R);
  }
}